// Round 1
// baseline (13985.959 us; speedup 1.0000x reference)
//
#include <hip/hip_runtime.h>

#define T_STEPS 128
#define BATCH 128
#define DX 1024
#define DH 1024
// gates computed: F, G, O, R  (I is implied by it = 1 - ft)
#define NG4 4096   // 4 * DH

__global__ void init_state(const float* __restrict__ h0, const float* __restrict__ c0,
                           float* __restrict__ h, float* __restrict__ c) {
    int i = blockIdx.x * blockDim.x + threadIdx.x;
    if (i < BATCH * DH) { h[i] = h0[i]; c[i] = c0[i]; }
}

// GEMM: g[b][n] = bx[DH+n] + bh[DH+n] + sum_k in[b][k] * W[DH+n][k]
// virtual K = 2048 (k < 1024 -> x/Wx, else h/Wh). BM=32, BN=64, BK=32.
__global__ __launch_bounds__(256) void gemm_gates(
    const float* __restrict__ x,   // [B][DX] slice at timestep t
    const float* __restrict__ h,   // [B][DH]
    const float* __restrict__ Wx,  // [5*DH][DX]
    const float* __restrict__ Wh,  // [5*DH][DH]
    const float* __restrict__ bx,  // [5*DH]
    const float* __restrict__ bh,  // [5*DH]
    float* __restrict__ g)         // [B][NG4]
{
    __shared__ float As[32][33];
    __shared__ float Bs[64][33];
    const int tid = threadIdx.x;
    const int row0 = blockIdx.x * 32;   // batch tile (4 tiles)
    const int n0   = blockIdx.y * 64;   // gate-col tile (64 tiles)

    const int lane = tid & 15;   // column group: cols lane + 16*j
    const int rg   = tid >> 4;   // row group:    rows rg*2 + i

    float acc[2][4] = {{0.f,0.f,0.f,0.f},{0.f,0.f,0.f,0.f}};

    for (int kt = 0; kt < 2048 / 32; ++kt) {
        const int k0 = kt * 32;
        // stage A tile 32x32: one float4 per thread
        {
            const int ar = tid >> 3;
            const int ac = (tid & 7) * 4;
            const int k  = k0 + ac;
            const float* src = (k < DX) ? (x + (size_t)(row0 + ar) * DX + k)
                                        : (h + (size_t)(row0 + ar) * DH + (k - DX));
            float4 v = *reinterpret_cast<const float4*>(src);
            As[ar][ac + 0] = v.x; As[ar][ac + 1] = v.y;
            As[ar][ac + 2] = v.z; As[ar][ac + 3] = v.w;
        }
        // stage B tile 64x32: two float4 per thread
        {
            const int ac = (tid & 7) * 4;
            const int k  = k0 + ac;
            #pragma unroll
            for (int r = 0; r < 2; ++r) {
                const int br = (tid >> 3) * 2 + r;
                const int jw = DH + n0 + br;   // skip unused I-gate chunk
                const float* src = (k < DX) ? (Wx + (size_t)jw * DX + k)
                                            : (Wh + (size_t)jw * DH + (k - DX));
                float4 v = *reinterpret_cast<const float4*>(src);
                Bs[br][ac + 0] = v.x; Bs[br][ac + 1] = v.y;
                Bs[br][ac + 2] = v.z; Bs[br][ac + 3] = v.w;
            }
        }
        __syncthreads();
        #pragma unroll
        for (int kk = 0; kk < 32; ++kk) {
            const float a0 = As[rg * 2 + 0][kk];
            const float a1 = As[rg * 2 + 1][kk];
            const float b0 = Bs[lane +  0][kk];
            const float b1 = Bs[lane + 16][kk];
            const float b2 = Bs[lane + 32][kk];
            const float b3 = Bs[lane + 48][kk];
            acc[0][0] += a0 * b0; acc[0][1] += a0 * b1;
            acc[0][2] += a0 * b2; acc[0][3] += a0 * b3;
            acc[1][0] += a1 * b0; acc[1][1] += a1 * b1;
            acc[1][2] += a1 * b2; acc[1][3] += a1 * b3;
        }
        __syncthreads();
    }

    #pragma unroll
    for (int i = 0; i < 2; ++i) {
        const int b = row0 + rg * 2 + i;
        #pragma unroll
        for (int j = 0; j < 4; ++j) {
            const int n = n0 + lane + 16 * j;
            g[(size_t)b * NG4 + n] = acc[i][j] + bx[DH + n] + bh[DH + n];
        }
    }
}

__global__ void cell_update(const float* __restrict__ g, const float* __restrict__ m,
                            float* __restrict__ c, float* __restrict__ h,
                            float* __restrict__ out) {
    int i = blockIdx.x * blockDim.x + threadIdx.x;  // over B*DH
    if (i >= BATCH * DH) return;
    const int b = i >> 10;
    const int j = i & 1023;
    const float* gb = g + (size_t)b * NG4;
    const float gf = gb[j];
    const float gg = gb[1024 + j];
    const float go = gb[2048 + j];
    const float gr = gb[3072 + j];
    const float ft = 1.f / (1.f + expf(-gf));
    const float ot = 1.f / (1.f + expf(-go));
    const float rt = 1.f / (1.f + expf(-gr));
    const float gt = tanhf(gg);
    const float cv = ft * c[i] + (1.f - ft) * gt + rt * tanhf(m[i]);
    c[i] = cv;
    const float hv = ot * tanhf(cv);
    h[i] = hv;
    out[i] = hv;
}

extern "C" void kernel_launch(void* const* d_in, const int* in_sizes, int n_in,
                              void* d_out, int out_size, void* d_ws, size_t ws_size,
                              hipStream_t stream) {
    const float* inputs   = (const float*)d_in[0];  // [T][B][DX]
    const float* memories = (const float*)d_in[1];  // [T][B][DH]
    const float* h0       = (const float*)d_in[2];  // [B][DH]
    const float* c0       = (const float*)d_in[3];  // [B][DH]
    const float* Wx       = (const float*)d_in[4];  // [5*DH][DX]
    const float* bx       = (const float*)d_in[5];  // [5*DH]
    const float* Wh       = (const float*)d_in[6];  // [5*DH][DH]
    const float* bh       = (const float*)d_in[7];  // [5*DH]
    float* out = (float*)d_out;                     // [T][B][DH]

    float* ws = (float*)d_ws;
    float* h = ws;                       // B*DH
    float* c = ws + BATCH * DH;          // B*DH
    float* g = ws + 2 * BATCH * DH;      // B*NG4

    init_state<<<(BATCH * DH + 255) / 256, 256, 0, stream>>>(h0, c0, h, c);

    dim3 ggrid(128 / 32, NG4 / 64);  // (4, 64) = 256 blocks
    for (int t = 0; t < T_STEPS; ++t) {
        gemm_gates<<<ggrid, 256, 0, stream>>>(
            inputs + (size_t)t * BATCH * DX, h, Wx, Wh, bx, bh, g);
        cell_update<<<(BATCH * DH + 255) / 256, 256, 0, stream>>>(
            g, memories + (size_t)t * BATCH * DH, c, h,
            out + (size_t)t * BATCH * DH);
    }
}

// Round 2
// 2157.554 us; speedup vs baseline: 6.4823x; 6.4823x over previous
//
#include <hip/hip_runtime.h>
#include <hip/hip_bf16.h>

#define T_STEPS 128
#define BATCH 128
#define DX 1024
#define DH 1024

typedef __attribute__((ext_vector_type(8))) short short8;
typedef __attribute__((ext_vector_type(4))) float f32x4;

static __device__ __forceinline__ unsigned short f2bf(float f) {
    union { float f; unsigned u; } v; v.f = f;
    unsigned r = v.u + 0x7fffu + ((v.u >> 16) & 1u);   // round-nearest-even
    return (unsigned short)(r >> 16);
}

// Permuted bf16 weights: perm row p = js*32 + g*8 + jj  (js=j>>3, jj=j&7, g in
// {F,G,O,R} = orig gate chunks 1..4). K-major 2048 (x-part 0..1023, h-part 1024..2047).
__global__ __launch_bounds__(256) void prep_w(const float* __restrict__ Wx,
                                              const float* __restrict__ Wh,
                                              const float* __restrict__ bx,
                                              const float* __restrict__ bh,
                                              unsigned short* __restrict__ Wp,
                                              float* __restrict__ bp) {
    const int p  = blockIdx.x;               // 0..4095
    const int js = p >> 5, g = (p >> 3) & 3, jj = p & 7;
    const int srow = (g + 1) * 1024 + js * 8 + jj;
    const int k = threadIdx.x * 8;           // 0..2040
    const float* src = (k < DX) ? (Wx + (size_t)srow * DX + k)
                                : (Wh + (size_t)srow * DH + (k - DX));
    float4 lo = reinterpret_cast<const float4*>(src)[0];
    float4 hi = reinterpret_cast<const float4*>(src)[1];
    union { unsigned short u[8]; short8 v; } pk;
    pk.u[0]=f2bf(lo.x); pk.u[1]=f2bf(lo.y); pk.u[2]=f2bf(lo.z); pk.u[3]=f2bf(lo.w);
    pk.u[4]=f2bf(hi.x); pk.u[5]=f2bf(hi.y); pk.u[6]=f2bf(hi.z); pk.u[7]=f2bf(hi.w);
    *reinterpret_cast<short8*>(Wp + (size_t)p * 2048 + k) = pk.v;
    if (threadIdx.x == 0) bp[p] = bx[srow] + bh[srow];
}

__global__ __launch_bounds__(256) void prep_x(const float* __restrict__ x,
                                              unsigned short* __restrict__ Xb) {
    const size_t i8 = ((size_t)blockIdx.x * 256 + threadIdx.x) * 8;
    float4 lo = reinterpret_cast<const float4*>(x + i8)[0];
    float4 hi = reinterpret_cast<const float4*>(x + i8)[1];
    union { unsigned short u[8]; short8 v; } pk;
    pk.u[0]=f2bf(lo.x); pk.u[1]=f2bf(lo.y); pk.u[2]=f2bf(lo.z); pk.u[3]=f2bf(lo.w);
    pk.u[4]=f2bf(hi.x); pk.u[5]=f2bf(hi.y); pk.u[6]=f2bf(hi.z); pk.u[7]=f2bf(hi.w);
    *reinterpret_cast<short8*>(Xb + i8) = pk.v;
}

__global__ __launch_bounds__(256) void init_state(const float* __restrict__ h0,
                                                  const float* __restrict__ c0,
                                                  unsigned short* __restrict__ hb,
                                                  float* __restrict__ c) {
    const int i = blockIdx.x * 256 + threadIdx.x;   // 131072 total
    hb[i] = f2bf(h0[i]);
    c[i] = c0[i];
}

// One timestep, fully fused: 4-gate GEMM slice (bf16 MFMA) + bias + cell update.
// Grid 256 WGs: bid = js*2 + bh. WG owns batch rows [bh*64, +64), j-cols
// [js*8, +8) i.e. perm rows [js*32, +32). 4 waves split K (wave*512..+512);
// waves 0-1 cover the x-part (k<1024), waves 2-3 the h-part. LDS reduction
// then fused sigmoid/tanh update. h is ping-ponged across steps (bf16).
template<bool XBF16>
__global__ __launch_bounds__(256) void fused_step(
    const void* __restrict__ xsrc,           // bf16 X_t or f32 x_t [B][DX]
    const float* __restrict__ mem,           // [B][DH] f32
    const unsigned short* __restrict__ Wp,   // [4096][2048] bf16
    const float* __restrict__ bp,            // [4096]
    const unsigned short* __restrict__ hin,  // [B][DH] bf16
    unsigned short* __restrict__ hout,       // [B][DH] bf16
    float* __restrict__ c,                   // [B][DH] f32 (rw)
    float* __restrict__ outt)                // [B][DH] f32
{
    const int bid = blockIdx.x;
    const int js  = bid >> 1;
    const int bh  = bid & 1;
    const int tid = threadIdx.x;
    const int wave = tid >> 6;
    const int lane = tid & 63;
    const int m16 = lane & 15;
    const int k8  = (lane >> 4) * 8;
    const int kw  = wave * 512;              // this wave's virtual-K start

    f32x4 acc[4][2] = {};

    const unsigned short* brow0 = Wp + (size_t)(js * 32 + m16) * 2048 + kw + k8;
    const unsigned short* brow1 = brow0 + 16 * 2048;
    const int b0 = bh * 64 + m16;            // A row for M-tile 0

    #pragma unroll
    for (int ks = 0; ks < 16; ++ks) {
        const int kv = kw + ks * 32 + k8;    // virtual k (0..2047)
        short8 a[4], bfr[2];
        bfr[0] = *reinterpret_cast<const short8*>(brow0 + ks * 32);
        bfr[1] = *reinterpret_cast<const short8*>(brow1 + ks * 32);
        if (XBF16 || kv >= DX) {             // wave-uniform branch
            const unsigned short* asrc = (kv < DX)
                ? ((const unsigned short*)xsrc + (size_t)b0 * DX + kv)
                : (hin + (size_t)b0 * DH + (kv - DX));
            #pragma unroll
            for (int mt = 0; mt < 4; ++mt)
                a[mt] = *reinterpret_cast<const short8*>(asrc + (size_t)mt * 16 * 1024);
        } else {
            const float* af = (const float*)xsrc + (size_t)b0 * DX + kv;
            #pragma unroll
            for (int mt = 0; mt < 4; ++mt) {
                float4 lo = reinterpret_cast<const float4*>(af + (size_t)mt * 16 * 1024)[0];
                float4 hi = reinterpret_cast<const float4*>(af + (size_t)mt * 16 * 1024)[1];
                union { unsigned short u[8]; short8 v; } pk;
                pk.u[0]=f2bf(lo.x); pk.u[1]=f2bf(lo.y); pk.u[2]=f2bf(lo.z); pk.u[3]=f2bf(lo.w);
                pk.u[4]=f2bf(hi.x); pk.u[5]=f2bf(hi.y); pk.u[6]=f2bf(hi.z); pk.u[7]=f2bf(hi.w);
                a[mt] = pk.v;
            }
        }
        #pragma unroll
        for (int mt = 0; mt < 4; ++mt) {
            acc[mt][0] = __builtin_amdgcn_mfma_f32_16x16x32_bf16(a[mt], bfr[0], acc[mt][0], 0, 0, 0);
            acc[mt][1] = __builtin_amdgcn_mfma_f32_16x16x32_bf16(a[mt], bfr[1], acc[mt][1], 0, 0, 0);
        }
    }

    // partial sums: pl[wave][batch-row-in-WG][perm-col]
    __shared__ float pl[4][64][33];
    #pragma unroll
    for (int mt = 0; mt < 4; ++mt) {
        const int row = mt * 16 + (lane >> 4) * 4;
        #pragma unroll
        for (int nt = 0; nt < 2; ++nt)
            #pragma unroll
            for (int r = 0; r < 4; ++r)
                pl[wave][row + r][nt * 16 + m16] = acc[mt][nt][r];
    }
    __syncthreads();

    // K-reduction across 4 waves + bias + cell update. 512 elems, 2 per thread.
    #pragma unroll
    for (int e2 = 0; e2 < 2; ++e2) {
        const int e  = tid * 2 + e2;
        const int br = e >> 3, jj = e & 7;
        float gs[4];
        #pragma unroll
        for (int g = 0; g < 4; ++g) {
            const int col = g * 8 + jj;
            gs[g] = pl[0][br][col] + pl[1][br][col] + pl[2][br][col] + pl[3][br][col]
                  + bp[js * 32 + col];
        }
        const int gi = (bh * 64 + br) * 1024 + js * 8 + jj;
        const float ft = 1.f / (1.f + expf(-gs[0]));
        const float gt = tanhf(gs[1]);
        const float ot = 1.f / (1.f + expf(-gs[2]));
        const float rt = 1.f / (1.f + expf(-gs[3]));
        const float cv = ft * c[gi] + (1.f - ft) * gt + rt * tanhf(mem[gi]);
        c[gi] = cv;
        const float hv = ot * tanhf(cv);
        hout[gi] = f2bf(hv);
        outt[gi] = hv;
    }
}

extern "C" void kernel_launch(void* const* d_in, const int* in_sizes, int n_in,
                              void* d_out, int out_size, void* d_ws, size_t ws_size,
                              hipStream_t stream) {
    const float* inputs   = (const float*)d_in[0];
    const float* memories = (const float*)d_in[1];
    const float* h0       = (const float*)d_in[2];
    const float* c0       = (const float*)d_in[3];
    const float* Wx       = (const float*)d_in[4];
    const float* bx       = (const float*)d_in[5];
    const float* Wh       = (const float*)d_in[6];
    const float* bh       = (const float*)d_in[7];
    float* out = (float*)d_out;

    char* ws = (char*)d_ws;
    size_t off = 0;
    auto alloc = [&](size_t bytes) {
        char* p = ws + off;
        off = (off + bytes + 255) & ~(size_t)255;
        return p;
    };
    unsigned short* Wp  = (unsigned short*)alloc((size_t)4096 * 2048 * 2);
    float*          bp  = (float*)alloc(4096 * 4);
    float*          c   = (float*)alloc((size_t)BATCH * DH * 4);
    unsigned short* hb0 = (unsigned short*)alloc((size_t)BATCH * DH * 2);
    unsigned short* hb1 = (unsigned short*)alloc((size_t)BATCH * DH * 2);
    const size_t x_need = (size_t)T_STEPS * BATCH * DX * 2;
    const bool use_xb = (ws_size >= off + x_need + 256);
    unsigned short* Xb = use_xb ? (unsigned short*)alloc(x_need) : nullptr;

    prep_w<<<4096, 256, 0, stream>>>(Wx, Wh, bx, bh, Wp, bp);
    init_state<<<512, 256, 0, stream>>>(h0, c0, hb0, c);
    if (use_xb) prep_x<<<8192, 256, 0, stream>>>(inputs, Xb);

    for (int t = 0; t < T_STEPS; ++t) {
        const unsigned short* hi_ = (t & 1) ? hb1 : hb0;
        unsigned short*       ho_ = (t & 1) ? hb0 : hb1;
        const float* mem_t = memories + (size_t)t * BATCH * DH;
        float*       out_t = out + (size_t)t * BATCH * DH;
        if (use_xb) {
            const void* xs = (const void*)(Xb + (size_t)t * BATCH * DX);
            fused_step<true><<<256, 256, 0, stream>>>(xs, mem_t, Wp, bp, hi_, ho_, c, out_t);
        } else {
            const void* xs = (const void*)(inputs + (size_t)t * BATCH * DX);
            fused_step<false><<<256, 256, 0, stream>>>(xs, mem_t, Wp, bp, hi_, ho_, c, out_t);
        }
    }
}

// Round 3
// 1664.186 us; speedup vs baseline: 8.4041x; 1.2965x over previous
//
#include <hip/hip_runtime.h>

#define T_STEPS 128
#define BATCH   128
#define DX      1024
#define DH      1024
#define BDH     (BATCH * DH)   // 131072
#define BDX     (BATCH * DX)

typedef __attribute__((ext_vector_type(8)))  short short8;
typedef __attribute__((ext_vector_type(16))) float f32x16;

static __device__ __forceinline__ unsigned short f2bf(float f) {
    union { float f; unsigned u; } v; v.f = f;
    unsigned r = v.u + 0x7fffu + ((v.u >> 16) & 1u);   // RNE
    return (unsigned short)(r >> 16);
}

__global__ __launch_bounds__(256) void prep_x(const float* __restrict__ x,
                                              unsigned short* __restrict__ Xb) {
    const size_t i8 = ((size_t)blockIdx.x * 256 + threadIdx.x) * 8;
    float4 lo = reinterpret_cast<const float4*>(x + i8)[0];
    float4 hi = reinterpret_cast<const float4*>(x + i8)[1];
    union { unsigned short u[8]; short8 v; } pk;
    pk.u[0]=f2bf(lo.x); pk.u[1]=f2bf(lo.y); pk.u[2]=f2bf(lo.z); pk.u[3]=f2bf(lo.w);
    pk.u[4]=f2bf(hi.x); pk.u[5]=f2bf(hi.y); pk.u[6]=f2bf(hi.z); pk.u[7]=f2bf(hi.w);
    *reinterpret_cast<short8*>(Xb + i8) = pk.v;
}

// seed hseq slab 0 with bf16(h0); zero the barrier words
__global__ __launch_bounds__(256) void init_seed(const float* __restrict__ h0,
                                                 unsigned short* __restrict__ hseq,
                                                 unsigned* __restrict__ bar) {
    const int i = blockIdx.x * 256 + threadIdx.x;   // 131072
    hseq[i] = f2bf(h0[i]);
    if (blockIdx.x == 0 && threadIdx.x < 128) bar[threadIdx.x] = 0;
}

// Persistent kernel: 256 WGs x 256 thr. WG(bid): js=bid>>1 (8 j-cols => 32 perm
// rows), bhh=bid&1 (64 batch rows). Weights (gates F,G,O,R; I elided) live in
// LDS for all 128 steps, XOR-swizzled. Waves: mh=wave>>1 (batch 32-half),
// kh=wave&1 (K 1024-half; kh=0 -> x, kh=1 -> h). h passes between steps via a
// ring hseq[t] written through to LLC (agent-scope stores) so plain cached
// loads never see stale data; steps separated by a 2x128-WG epoch barrier.
template<bool XBF16>
__global__ __launch_bounds__(256, 1) void eplstm_persistent(
    const void*  __restrict__ xsrc,           // bf16 Xb or f32 inputs [T][B][DX]
    const float* __restrict__ mem,            // [T][B][DH]
    const float* __restrict__ Wx,             // [5*DH][DX]
    const float* __restrict__ Wh,             // [5*DH][DH]
    const float* __restrict__ bxp,            // [5*DH]
    const float* __restrict__ bhp,            // [5*DH]
    const float* __restrict__ c0,             // [B][DH]
    unsigned short* __restrict__ hseq,        // [T+1][B][DH] bf16 ring
    float* __restrict__ out,                  // [T][B][DH]
    unsigned* __restrict__ bar)               // barrier words
{
    extern __shared__ char smem[];            // [0,128K): W swz; then pl[4][32][33] f32
    float* pl = reinterpret_cast<float*>(smem + 131072);

    const int bid = blockIdx.x;
    const int js  = bid >> 1;
    const int bhh = bid & 1;
    const int tid = threadIdx.x;

    // ---- one-time: stage swizzled bf16 weights into LDS ----
    {
        const int prow = tid >> 3;            // perm row local 0..31
        const int g = prow >> 3, jj = prow & 7;
        const int srow = (g + 1) * 1024 + js * 8 + jj;   // skip I chunk
        const int kc = (tid & 7) * 256;
        const int sw = (prow & 7) << 4;
        for (int it = 0; it < 32; ++it) {
            const int k = kc + it * 8;
            const float* src = (k < DX) ? (Wx + (size_t)srow * DX + k)
                                        : (Wh + (size_t)srow * DH + (k - DX));
            float4 lo = reinterpret_cast<const float4*>(src)[0];
            float4 hi = reinterpret_cast<const float4*>(src)[1];
            union { unsigned short u[8]; short8 v; } pk;
            pk.u[0]=f2bf(lo.x); pk.u[1]=f2bf(lo.y); pk.u[2]=f2bf(lo.z); pk.u[3]=f2bf(lo.w);
            pk.u[4]=f2bf(hi.x); pk.u[5]=f2bf(hi.y); pk.u[6]=f2bf(hi.z); pk.u[7]=f2bf(hi.w);
            *reinterpret_cast<short8*>(smem + prow * 4096 + ((k * 2) ^ sw)) = pk.v;
        }
    }

    // ---- per-thread epilogue constants ----
    const int e0   = tid * 2;
    const int bl   = e0 >> 3;                 // batch-local 0..63
    const int jj0  = e0 & 7;                  // even
    const int brow_g = bhh * 64 + bl;         // global batch row
    const size_t oidx = (size_t)brow_g * DH + js * 8 + jj0;
    float biasv[2][4];
    #pragma unroll
    for (int e2 = 0; e2 < 2; ++e2)
        #pragma unroll
        for (int g = 0; g < 4; ++g) {
            const int srow = (g + 1) * 1024 + js * 8 + jj0 + e2;
            biasv[e2][g] = bxp[srow] + bhp[srow];
        }
    float2 creg = *reinterpret_cast<const float2*>(c0 + oidx);
    const int mh_e = bl >> 5, rr = bl & 31;

    // ---- MFMA loop constants ----
    const int wave = tid >> 6;
    const int lane = tid & 63;
    const int mh = wave >> 1, kh = wave & 1;
    const int arow   = bhh * 64 + mh * 32 + (lane & 31);
    const int k8     = (lane >> 5) * 8;
    const int brow   = lane & 31;
    const char* bbase = smem + brow * 4096;
    const int swz    = (brow & 7) << 4;
    const int kbyte0 = kh * 2048 + k8 * 2;

    __syncthreads();                          // weights staged

    for (int t = 0; t < T_STEPS; ++t) {
        f32x16 ac0 = {}, ac1 = {}, ac2 = {}, ac3 = {};
        if (XBF16 || kh == 1) {
            const unsigned short* Ab = kh
                ? (hseq + (size_t)t * BDH + (size_t)arow * DH + k8)
                : ((const unsigned short*)xsrc + (size_t)t * BDX + (size_t)arow * DX + k8);
            #pragma unroll 8
            for (int ks = 0; ks < 64; ++ks) {
                short8 a = *reinterpret_cast<const short8*>(Ab + ks * 16);
                short8 b = *reinterpret_cast<const short8*>(bbase + ((kbyte0 + ks * 32) ^ swz));
                if      ((ks & 3) == 0) ac0 = __builtin_amdgcn_mfma_f32_32x32x16_bf16(a, b, ac0, 0, 0, 0);
                else if ((ks & 3) == 1) ac1 = __builtin_amdgcn_mfma_f32_32x32x16_bf16(a, b, ac1, 0, 0, 0);
                else if ((ks & 3) == 2) ac2 = __builtin_amdgcn_mfma_f32_32x32x16_bf16(a, b, ac2, 0, 0, 0);
                else                    ac3 = __builtin_amdgcn_mfma_f32_32x32x16_bf16(a, b, ac3, 0, 0, 0);
            }
        } else {  // f32 x fallback (kh==0 waves)
            const float* Af = (const float*)xsrc + (size_t)t * BDX + (size_t)arow * DX + k8;
            #pragma unroll 4
            for (int ks = 0; ks < 64; ++ks) {
                float4 lo = reinterpret_cast<const float4*>(Af + ks * 16)[0];
                float4 hi = reinterpret_cast<const float4*>(Af + ks * 16)[1];
                union { unsigned short u[8]; short8 v; } pk;
                pk.u[0]=f2bf(lo.x); pk.u[1]=f2bf(lo.y); pk.u[2]=f2bf(lo.z); pk.u[3]=f2bf(lo.w);
                pk.u[4]=f2bf(hi.x); pk.u[5]=f2bf(hi.y); pk.u[6]=f2bf(hi.z); pk.u[7]=f2bf(hi.w);
                short8 a = pk.v;
                short8 b = *reinterpret_cast<const short8*>(bbase + ((kbyte0 + ks * 32) ^ swz));
                if      ((ks & 3) == 0) ac0 = __builtin_amdgcn_mfma_f32_32x32x16_bf16(a, b, ac0, 0, 0, 0);
                else if ((ks & 3) == 1) ac1 = __builtin_amdgcn_mfma_f32_32x32x16_bf16(a, b, ac1, 0, 0, 0);
                else if ((ks & 3) == 2) ac2 = __builtin_amdgcn_mfma_f32_32x32x16_bf16(a, b, ac2, 0, 0, 0);
                else                    ac3 = __builtin_amdgcn_mfma_f32_32x32x16_bf16(a, b, ac3, 0, 0, 0);
            }
        }
        f32x16 r = (ac0 + ac1) + (ac2 + ac3);

        // partials -> LDS: pl[wave][c_row][c_col]
        #pragma unroll
        for (int i = 0; i < 16; ++i) {
            const int row = (i & 3) + 8 * (i >> 2) + 4 * (lane >> 5);
            pl[(wave * 32 + row) * 33 + brow] = r[i];
        }
        __syncthreads();

        // epilogue: 2 elements per thread
        const float2 mt2 = *reinterpret_cast<const float2*>(
            mem + (size_t)t * BDH + oidx);
        float hv[2];
        #pragma unroll
        for (int e2 = 0; e2 < 2; ++e2) {
            const int jj = jj0 + e2;
            float gs[4];
            #pragma unroll
            for (int g = 0; g < 4; ++g) {
                const int col = g * 8 + jj;
                gs[g] = pl[((mh_e * 2 + 0) * 32 + rr) * 33 + col]
                      + pl[((mh_e * 2 + 1) * 32 + rr) * 33 + col]
                      + biasv[e2][g];
            }
            const float ft = 1.f / (1.f + expf(-gs[0]));
            const float gt = tanhf(gs[1]);
            const float ot = 1.f / (1.f + expf(-gs[2]));
            const float rt = 1.f / (1.f + expf(-gs[3]));
            const float cin = e2 ? creg.y : creg.x;
            const float mv  = e2 ? mt2.y : mt2.x;
            const float cv = ft * cin + (1.f - ft) * gt + rt * tanhf(mv);
            if (e2) creg.y = cv; else creg.x = cv;
            hv[e2] = ot * tanhf(cv);
        }
        *reinterpret_cast<float2*>(out + (size_t)t * BDH + oidx) = make_float2(hv[0], hv[1]);
        const unsigned hp = (unsigned)f2bf(hv[0]) | ((unsigned)f2bf(hv[1]) << 16);
        __hip_atomic_store((unsigned*)(hseq + (size_t)(t + 1) * BDH + oidx), hp,
                           __ATOMIC_RELAXED, __HIP_MEMORY_SCOPE_AGENT);

        __syncthreads();   // pl reuse safety; all waves' stores drained (vmcnt0)
        if (t < T_STEPS - 1) {
            if (tid == 0) {
                const unsigned want = (unsigned)(t + 1);
                const unsigned arrived = __hip_atomic_fetch_add(
                    &bar[bhh * 32], 1u, __ATOMIC_RELAXED, __HIP_MEMORY_SCOPE_AGENT);
                if (arrived == want * 128u - 1u) {
                    __hip_atomic_store(&bar[64 + bhh * 32], want,
                                       __ATOMIC_RELAXED, __HIP_MEMORY_SCOPE_AGENT);
                } else {
                    while (__hip_atomic_load(&bar[64 + bhh * 32],
                                             __ATOMIC_RELAXED, __HIP_MEMORY_SCOPE_AGENT) < want)
                        __builtin_amdgcn_s_sleep(2);
                }
            }
            __syncthreads();
        }
    }
}

extern "C" void kernel_launch(void* const* d_in, const int* in_sizes, int n_in,
                              void* d_out, int out_size, void* d_ws, size_t ws_size,
                              hipStream_t stream) {
    const float* inputs   = (const float*)d_in[0];
    const float* memories = (const float*)d_in[1];
    const float* h0       = (const float*)d_in[2];
    const float* c0       = (const float*)d_in[3];
    const float* Wx       = (const float*)d_in[4];
    const float* bx       = (const float*)d_in[5];
    const float* Wh       = (const float*)d_in[6];
    const float* bh_      = (const float*)d_in[7];
    float* outp = (float*)d_out;

    char* ws = (char*)d_ws;
    size_t off = 0;
    auto alloc = [&](size_t bytes) {
        char* p = ws + off;
        off = (off + bytes + 255) & ~(size_t)255;
        return p;
    };
    unsigned*       bar  = (unsigned*)alloc(128 * sizeof(unsigned));
    unsigned short* hseq = (unsigned short*)alloc((size_t)(T_STEPS + 1) * BDH * 2);
    const size_t x_need = (size_t)T_STEPS * BDX * 2;
    const bool use_xb = (ws_size >= off + x_need + 256);
    unsigned short* Xb = use_xb ? (unsigned short*)alloc(x_need) : nullptr;

    init_seed<<<512, 256, 0, stream>>>(h0, hseq, bar);
    if (use_xb) prep_x<<<8192, 256, 0, stream>>>(inputs, Xb);

    const unsigned smem_bytes = 131072 + 4 * 32 * 33 * 4;   // 147968
    const void* xsrc = use_xb ? (const void*)Xb : (const void*)inputs;

    if (use_xb) {
        (void)hipFuncSetAttribute((const void*)eplstm_persistent<true>,
                                  hipFuncAttributeMaxDynamicSharedMemorySize, smem_bytes);
        void* kargs[] = { (void*)&xsrc, (void*)&memories, (void*)&Wx, (void*)&Wh,
                          (void*)&bx, (void*)&bh_, (void*)&c0, (void*)&hseq,
                          (void*)&outp, (void*)&bar };
        hipError_t err = hipLaunchCooperativeKernel(
            (const void*)eplstm_persistent<true>, dim3(256), dim3(256),
            kargs, smem_bytes, stream);
        if (err != hipSuccess) {
            eplstm_persistent<true><<<256, 256, smem_bytes, stream>>>(
                xsrc, memories, Wx, Wh, bx, bh_, c0, hseq, outp, bar);
        }
    } else {
        (void)hipFuncSetAttribute((const void*)eplstm_persistent<false>,
                                  hipFuncAttributeMaxDynamicSharedMemorySize, smem_bytes);
        void* kargs[] = { (void*)&xsrc, (void*)&memories, (void*)&Wx, (void*)&Wh,
                          (void*)&bx, (void*)&bh_, (void*)&c0, (void*)&hseq,
                          (void*)&outp, (void*)&bar };
        hipError_t err = hipLaunchCooperativeKernel(
            (const void*)eplstm_persistent<false>, dim3(256), dim3(256),
            kargs, smem_bytes, stream);
        if (err != hipSuccess) {
            eplstm_persistent<false><<<256, 256, smem_bytes, stream>>>(
                xsrc, memories, Wx, Wh, bx, bh_, c0, hseq, outp, bar);
        }
    }
}